// Round 2
// baseline (370.690 us; speedup 1.0000x reference)
//
#include <hip/hip_runtime.h>

// vol[n,d,h,w] = sum_c L[n,c,h,w] * R[n,c,h,w-d], 0 if w<d
// N=4, C=128, H=160, W=320, D=48, fp32 in/out.
//
// One block per (n,h) row. Stage L-row and R-row into LDS as half2 channel
// pairs (w-major), 8 chunks of 16 channels. Each thread owns a 5w x 16j
// register tile (j = w-d, window 8-aligned so R reads are ds_read_b128),
// accumulates with v_dot2_f32_f16, scatters valid d's at the end.

#define NN 4
#define CC 128
#define HH 160
#define WW 320
#define DD 48
#define HWs (HH * WW)

typedef _Float16 h2 __attribute__((ext_vector_type(2)));
typedef __fp16 h2raw __attribute__((ext_vector_type(2)));

__device__ __forceinline__ h2 pack2(float a, float b) {
  h2raw r = __builtin_amdgcn_cvt_pkrtz(a, b);  // v_cvt_pkrtz_f16_f32
  union { h2raw r; h2 h; } u;
  u.r = r;
  return u.h;
}

__device__ __forceinline__ h2 as_h2(float f) {
  union { float f; h2 h; } u;
  u.f = f;
  return u.h;
}

__device__ __forceinline__ float dot2(h2 a, h2 b, float c) {
  return __builtin_amdgcn_fdot2(a, b, c, false);  // v_dot2_f32_f16
}

__global__ __launch_bounds__(256, 2)
void corr_kernel(const float* __restrict__ L, const float* __restrict__ R,
                 float* __restrict__ out) {
  // 8 channel-pairs per chunk; R row padded to [-48, 336) in j (zeros outside [0,W))
  __shared__ __align__(16) h2 Lsp[8][WW];    // 10.0 KB
  __shared__ __align__(16) h2 Rsp[8][384];   // 12.0 KB

  const int tid = threadIdx.x;
  const int wg = tid & 63;       // 64 w-groups, Tw=5 contiguous w's
  const int jg = tid >> 6;       // 4 j-groups, Tj=16 contiguous j's
  const int bid = blockIdx.x;
  const int n = bid / HH;
  const int h = bid - n * HH;

  const int w0 = 5 * wg;
  // thread's j-window start in shifted js-space (js = j + 48), 8-aligned
  const int js0 = ((w0 + 1) & ~7) + 16 * jg;

  const size_t base = (size_t)n * CC * HWs + (size_t)h * WW;
  const float* Lb = L + base;
  const float* Rb = R + base;

  float acc[5][16];
#pragma unroll
  for (int i = 0; i < 5; ++i)
#pragma unroll
    for (int k = 0; k < 16; ++k) acc[i][k] = 0.f;

  for (int q = 0; q < 8; ++q) {
    const int c0 = 16 * q;
    // ---- stage 16 channels (8 half2-pairs) of L and R rows into LDS ----
#pragma unroll
    for (int cpl = 0; cpl < 8; ++cpl) {
      const float* La = Lb + (size_t)(c0 + 2 * cpl) * HWs;
      const float* Lc = La + HWs;
      for (int w = tid; w < WW; w += 256)
        Lsp[cpl][w] = pack2(La[w], Lc[w]);
      const float* Ra = Rb + (size_t)(c0 + 2 * cpl) * HWs;
      const float* Rc = Ra + HWs;
      for (int js = tid; js < 384; js += 256) {
        const int j = js - 48;
        float a = 0.f, b = 0.f;
        if (j >= 0 && j < WW) { a = Ra[j]; b = Rc[j]; }
        Rsp[cpl][js] = pack2(a, b);
      }
    }
    __syncthreads();

    // ---- compute: 8 channel-pairs, 5x16 register tile each ----
#pragma unroll
    for (int cpl = 0; cpl < 8; ++cpl) {
      h2 lv[5];
#pragma unroll
      for (int i = 0; i < 5; ++i) lv[i] = Lsp[cpl][w0 + i];

      const float4* rp = reinterpret_cast<const float4*>(&Rsp[cpl][js0]);
      h2 rv[16];
#pragma unroll
      for (int t = 0; t < 4; ++t) {
        float4 v = rp[t];
        rv[4 * t + 0] = as_h2(v.x);
        rv[4 * t + 1] = as_h2(v.y);
        rv[4 * t + 2] = as_h2(v.z);
        rv[4 * t + 3] = as_h2(v.w);
      }
#pragma unroll
      for (int i = 0; i < 5; ++i)
#pragma unroll
        for (int k = 0; k < 16; ++k)
          acc[i][k] = dot2(lv[i], rv[k], acc[i][k]);
    }
    __syncthreads();
  }

  // ---- epilogue: scatter valid (w, d) entries ----
#pragma unroll
  for (int i = 0; i < 5; ++i) {
    const int w = w0 + i;
#pragma unroll
    for (int k = 0; k < 16; ++k) {
      const int d = w + 48 - (js0 + k);  // d = w - j
      if (d >= 0 && d < DD)
        out[((size_t)(n * DD + d) * HH + h) * WW + w] = acc[i][k];
    }
  }
}

extern "C" void kernel_launch(void* const* d_in, const int* in_sizes, int n_in,
                              void* d_out, int out_size, void* d_ws, size_t ws_size,
                              hipStream_t stream) {
  const float* L = (const float*)d_in[0];
  const float* R = (const float*)d_in[1];
  float* out = (float*)d_out;
  corr_kernel<<<dim3(NN * HH), dim3(256), 0, stream>>>(L, R, out);
}

// Round 3
// 279.610 us; speedup vs baseline: 1.3257x; 1.3257x over previous
//
#include <hip/hip_runtime.h>

// vol[n,d,h,w] = sum_c L[n,c,h,w] * R[n,c,h,w-d], 0 if w<d
// N=4, C=128, H=160, W=320, D=48, fp32 in/out.
//
// 1280 blocks = (n,h) rows x 2 w-halves (160 w each) -> exactly 5 blocks/CU.
// Double-buffered LDS chunks of 16 channels, staged as half2 channel-pairs via
// float4 loads + cvt_pkrtz + ds_write_b128. Each thread: 5w x 8j register tile,
// v_dot2_f32_f16 accumulate, scatter valid (w,d) at the end.

#define NN 4
#define CC 128
#define HH 160
#define WW 320
#define DD 48
#define HWs (HH * WW)
#define WB 160   // w extent per block
#define RJ 208   // staged R extent in h2 (j in [wb-48, wb+160))

typedef _Float16 h2 __attribute__((ext_vector_type(2)));
typedef __fp16 h2raw __attribute__((ext_vector_type(2)));

union V4 { float4 f; h2 h[4]; };

__device__ __forceinline__ h2 pack2(float a, float b) {
  union { h2raw r; h2 h; } u;
  u.r = __builtin_amdgcn_cvt_pkrtz(a, b);  // v_cvt_pkrtz_f16_f32
  return u.h;
}

__device__ __forceinline__ float dot2(h2 a, h2 b, float c) {
  return __builtin_amdgcn_fdot2(a, b, c, false);  // v_dot2_f32_f16
}

__global__ __launch_bounds__(256, 5)
void corr_kernel(const float* __restrict__ L, const float* __restrict__ R,
                 float* __restrict__ out) {
  __shared__ __align__(16) h2 Lsp[2][8][WB];  // 10.0 KB
  __shared__ __align__(16) h2 Rsp[2][8][RJ];  // 13.0 KB

  const int tid = threadIdx.x;
  const int wg = tid & 31;   // 32 w-groups x 5 w
  const int jg = tid >> 5;   // 8 j-groups x 8 j
  const int bid = blockIdx.x;
  const int wsplit = bid & 1;
  const int row = bid >> 1;
  const int n = row / HH;
  const int h = row - n * HH;
  const int wb = wsplit * WB;

  const int u0 = 5 * wg;                  // w offset within block: w = wb+u0+i
  int S = (u0 + 1) & ~7;                  // 8-aligned 64-j window start (js space)
  if (S > RJ - 64) S = RJ - 64;           // clamp so window stays in [0, RJ)
  const int js0 = S + 8 * jg;             // this thread's 8-j slice

  const size_t base = (size_t)n * CC * HWs + (size_t)h * WW;
  const float* Lb = L + base + wb;
  const float* Rb = R + base + (wb - 48);  // Rb[js] = R[..., wb-48+js]

  float acc[5][8];
#pragma unroll
  for (int i = 0; i < 5; ++i)
#pragma unroll
    for (int k = 0; k < 8; ++k) acc[i][k] = 0.f;

  auto stage = [&](int q, int b) {
    const int c0 = 16 * q;
    // L: 8 cp x 40 float4-positions = 320 tasks
    for (int t = tid; t < 320; t += 256) {
      const int cp = t / 40, v = t - cp * 40;
      const float* p = Lb + (size_t)(c0 + 2 * cp) * HWs + 4 * v;
      const float4 a = *(const float4*)p;
      const float4 c = *(const float4*)(p + HWs);
      V4 u;
      u.h[0] = pack2(a.x, c.x); u.h[1] = pack2(a.y, c.y);
      u.h[2] = pack2(a.z, c.z); u.h[3] = pack2(a.w, c.w);
      *(float4*)&Lsp[b][cp][4 * v] = u.f;
    }
    // R: 8 cp x 52 float4-positions = 416 tasks (zero-fill j<0; 4-aligned so
    // a float4 is entirely valid or entirely padding)
    for (int t = tid; t < 416; t += 256) {
      const int cp = t / 52, v = t - cp * 52;
      float4 a = {0.f, 0.f, 0.f, 0.f}, c = {0.f, 0.f, 0.f, 0.f};
      if (wb - 48 + 4 * v >= 0) {
        const float* p = Rb + (size_t)(c0 + 2 * cp) * HWs + 4 * v;
        a = *(const float4*)p;
        c = *(const float4*)(p + HWs);
      }
      V4 u;
      u.h[0] = pack2(a.x, c.x); u.h[1] = pack2(a.y, c.y);
      u.h[2] = pack2(a.z, c.z); u.h[3] = pack2(a.w, c.w);
      *(float4*)&Rsp[b][cp][4 * v] = u.f;
    }
  };

  auto compute = [&](int b) {
#pragma unroll
    for (int cpl = 0; cpl < 8; ++cpl) {
      h2 lv[5];
#pragma unroll
      for (int i = 0; i < 5; ++i) lv[i] = Lsp[b][cpl][u0 + i];
      V4 r0, r1;
      r0.f = *(const float4*)&Rsp[b][cpl][js0];
      r1.f = *(const float4*)&Rsp[b][cpl][js0 + 4];
      h2 rv[8] = {r0.h[0], r0.h[1], r0.h[2], r0.h[3],
                  r1.h[0], r1.h[1], r1.h[2], r1.h[3]};
#pragma unroll
      for (int i = 0; i < 5; ++i)
#pragma unroll
        for (int k = 0; k < 8; ++k)
          acc[i][k] = dot2(lv[i], rv[k], acc[i][k]);
    }
  };

  stage(0, 0);
  __syncthreads();
  for (int q = 0; q < 8; ++q) {
    const int b = q & 1;
    if (q < 7) stage(q + 1, b ^ 1);  // prefetch next chunk into other buffer
    compute(b);
    __syncthreads();
  }

  // epilogue: d = w - j = u0+i+48-(js0+k); store valid entries
  float* ob = out + (size_t)n * DD * HWs + (size_t)h * WW + wb + u0;
#pragma unroll
  for (int i = 0; i < 5; ++i)
#pragma unroll
    for (int k = 0; k < 8; ++k) {
      const int d = u0 + i + 48 - (js0 + k);
      if (d >= 0 && d < DD) ob[(size_t)d * HWs + i] = acc[i][k];
    }
}

extern "C" void kernel_launch(void* const* d_in, const int* in_sizes, int n_in,
                              void* d_out, int out_size, void* d_ws, size_t ws_size,
                              hipStream_t stream) {
  const float* L = (const float*)d_in[0];
  const float* R = (const float*)d_in[1];
  float* out = (float*)d_out;
  corr_kernel<<<dim3(2 * NN * HH), dim3(256), 0, stream>>>(L, R, out);
}